// Round 1
// baseline (354.535 us; speedup 1.0000x reference)
//
#include <hip/hip_runtime.h>
#include <math.h>

// Problem constants (fixed by reference setup_inputs):
//   B=4, C=256, H=64, W=128, D=4, NSHIFT=9 -> 81 shifts, R=16 -> C/R=16
// out: [B, 81, H, W] fp32, out_size = 4*81*64*128 = 2654208
// ws usage: pooled [4*81*256] f32 + a [4*81*256] f32 = 663552 bytes total.

#define HH 64
#define WW 128
#define CC 256
#define BB 4

// ---------------------------------------------------------------------------
// Kernel A: pooled[b, s, c] = sum_{h,w} f1[b,c,h,w] * f2pad[b,c,h+i,w+j]
// (raw sum; /8192 applied in kernel B). One block per (b,c) plane.
// LDS: zero-padded f2 plane, 72 rows x 140 floats (35 float4 chunks/row).
// Chunk-stride 35 (== 3 mod 8) spreads each wave's b128 reads uniformly
// over all 32 banks (8 dwords/bank = minimal service time).
// ---------------------------------------------------------------------------
__global__ __launch_bounds__(256) void corr_pool_kernel(
    const float* __restrict__ f1, const float* __restrict__ f2,
    float* __restrict__ pooled) {
  const int t  = threadIdx.x;
  const int bc = blockIdx.x;                    // b*256 + c
  const float* f1p = f1 + (size_t)bc * (HH * WW);
  const float* f2p = f2 + (size_t)bc * (HH * WW);

  __shared__ float4 f2s4[72 * 35];              // 40,320 B padded f2 plane
  __shared__ float  rowpart[64 * 81];           // 20,736 B per-row partials

  // zero the padded plane (covers halo)
  const float4 z4 = make_float4(0.f, 0.f, 0.f, 0.f);
  for (int u = t; u < 72 * 35; u += 256) f2s4[u] = z4;
  __syncthreads();
  // fill interior: orig row r -> padded row r+4, orig chunk k -> padded chunk k+1
  for (int u = t; u < 2048; u += 256) {
    const int r = u >> 5, k = u & 31;
    const float4 v = *(const float4*)(f2p + (r << 7) + (k << 2));
    f2s4[(r + 4) * 35 + 1 + k] = v;
  }
  __syncthreads();

  const int h   = t >> 2;                       // 0..63
  const int seg = t & 3;
  const int w0  = seg << 5;                     // 0,32,64,96

  alignas(16) float f1r[32];
#pragma unroll
  for (int u = 0; u < 8; ++u)
    *(float4*)&f1r[4 * u] = *(const float4*)(f1p + (h << 7) + w0 + (u << 2));

  for (int i = 0; i < 9; ++i) {
    alignas(16) float f2r[40];
    const float4* src = &f2s4[(h + i) * 35 + (w0 >> 2)];
#pragma unroll
    for (int m = 0; m < 10; ++m) *(float4*)&f2r[4 * m] = src[m];

    float s9[9];
#pragma unroll
    for (int j = 0; j < 9; ++j) s9[j] = 0.f;
#pragma unroll
    for (int k = 0; k < 32; ++k) {
      const float a = f1r[k];
#pragma unroll
      for (int j = 0; j < 9; ++j) s9[j] += a * f2r[k + j];
    }
    // sum over the 4 seg-lanes (same row h): lanes differ in bits 0..1
#pragma unroll
    for (int j = 0; j < 9; ++j) {
      s9[j] += __shfl_xor(s9[j], 1);
      s9[j] += __shfl_xor(s9[j], 2);
    }
    if (seg == 0) {
#pragma unroll
      for (int j = 0; j < 9; ++j) rowpart[h * 81 + i * 9 + j] = s9[j];
    }
  }
  __syncthreads();

  if (t < 81) {
    float acc = 0.f;
    for (int r = 0; r < 64; ++r) acc += rowpart[r * 81 + t];
    const int b = bc >> 8, c = bc & 255;
    pooled[(size_t)(b * 81 + t) * 256 + c] = acc;   // raw sum
  }
}

// ---------------------------------------------------------------------------
// Kernel B: a[b,s,c] = sigmoid(W2 (W1 (pooled/8192) + b1) + b2)
// One block per (b,s) pair. 256 threads.
// ---------------------------------------------------------------------------
__global__ __launch_bounds__(256) void mlp_kernel(
    const float* __restrict__ pooled, const float* __restrict__ w1,
    const float* __restrict__ b1, const float* __restrict__ w2,
    const float* __restrict__ b2, float* __restrict__ a_out) {
  const int bs = blockIdx.x;                    // b*81 + s
  const int t  = threadIdx.x;
  __shared__ float p[256];
  __shared__ float hid[16];

  p[t] = pooled[(size_t)bs * 256 + t] * (1.0f / 8192.0f);
  __syncthreads();

  const int g = t >> 4, ln = t & 15;            // 16 groups of 16 lanes
  float acc = 0.f;
#pragma unroll
  for (int m = 0; m < 16; ++m) {
    const int c = (m << 4) + ln;
    acc += w1[(g << 8) + c] * p[c];
  }
  acc += __shfl_xor(acc, 1);
  acc += __shfl_xor(acc, 2);
  acc += __shfl_xor(acc, 4);
  acc += __shfl_xor(acc, 8);
  if (ln == 0) hid[g] = acc + b1[g];
  __syncthreads();

  float acc2 = b2[t];
#pragma unroll
  for (int k = 0; k < 16; ++k) acc2 += w2[(t << 4) + k] * hid[k];
  a_out[(size_t)bs * 256 + t] = 1.0f / (1.0f + __expf(-acc2));
}

// ---------------------------------------------------------------------------
// Kernel C: out[b, i*9+j, h, w] = (1/256) sum_c a[b,s,c]*f1[c,h,w]*f2[c,h+i-4,w+j-4]
// grid = b(4) x i(9) x rowtile(16); block = 128 threads = 4 rows x 32 float4-cols.
// i is block-uniform -> the 9 a-coefficient loads per channel are uniform
// (should scalarize to s_load). f2 rows double-buffered through LDS
// (1 barrier per channel); f1 read direct from global (used once per block).
// ---------------------------------------------------------------------------
__global__ __launch_bounds__(128) void out_kernel(
    const float* __restrict__ f1, const float* __restrict__ f2,
    const float* __restrict__ A, float* __restrict__ out) {
  const int blk = blockIdx.x;
  const int b   = blk / 144;
  const int rem = blk - b * 144;
  const int i   = rem >> 4;
  const int rt  = rem & 15;
  const int h0  = rt << 2;

  const int t    = threadIdx.x;
  const int r    = t >> 5;                      // 0..3
  const int cidx = t & 31;
  const int w0   = cidx << 2;
  const int h    = h0 + r;

  __shared__ float4 f2s[2][4 * 35];             // 2 x 2,240 B, row stride 35 chunks

  const float* f1b = f1 + (size_t)b * 256 * 8192;
  const float* f2b = f2 + (size_t)b * 256 * 8192;
  const float* Ab  = A + (size_t)(b * 81 + i * 9) * 256;  // Ab[j*256 + c]

  float acc[9][4];
#pragma unroll
  for (int j = 0; j < 9; ++j)
#pragma unroll
    for (int k = 0; k < 4; ++k) acc[j][k] = 0.f;

  const float4 z4 = make_float4(0.f, 0.f, 0.f, 0.f);
  // stage channel c's 4 shifted f2 rows (with zero halo) into buffer `buf`
  auto stage = [&](int c, int buf) {
    const float* f2plane = f2b + (size_t)c * 8192;
    for (int u = t; u < 136; u += 128) {        // 4 rows x 34 chunks
      const int rr = u / 34;
      const int kk = u - rr * 34;               // padded chunk col 0..33
      const int hr = h0 + rr + i - 4;
      float4 v = z4;
      if ((unsigned)hr < 64u && kk >= 1 && kk <= 32)
        v = *(const float4*)(f2plane + (hr << 7) + ((kk - 1) << 2));
      f2s[buf][rr * 35 + kk] = v;
    }
  };

  stage(0, 0);

  for (int c = 0; c < 256; ++c) {
    __syncthreads();                            // buf[c&1] ready
    const int buf = c & 1;
    if (c + 1 < 256) stage(c + 1, buf ^ 1);     // prefetch next channel

    float4 xv = *(const float4*)(f1b + (size_t)c * 8192 + (h << 7) + w0);
    alignas(16) float xx[4] = {xv.x, xv.y, xv.z, xv.w};

    alignas(16) float f2r[12];
    {
      const float4* srcp = &f2s[buf][r * 35 + cidx];  // padded cols w0..w0+11
      *(float4*)&f2r[0] = srcp[0];
      *(float4*)&f2r[4] = srcp[1];
      *(float4*)&f2r[8] = srcp[2];
    }

    float av[9];
#pragma unroll
    for (int j = 0; j < 9; ++j) av[j] = Ab[(j << 8) + c];  // block-uniform

#pragma unroll
    for (int j = 0; j < 9; ++j) {
      const float wj = av[j];
#pragma unroll
      for (int k = 0; k < 4; ++k) acc[j][k] += wj * (xx[k] * f2r[k + j]);
    }
  }

  const float inv = 1.0f / 256.0f;
#pragma unroll
  for (int j = 0; j < 9; ++j) {
    float4 o;
    o.x = acc[j][0] * inv;
    o.y = acc[j][1] * inv;
    o.z = acc[j][2] * inv;
    o.w = acc[j][3] * inv;
    *(float4*)(out + (((size_t)(b * 81 + i * 9 + j) * 64 + h) << 7) + w0) = o;
  }
}

// ---------------------------------------------------------------------------
extern "C" void kernel_launch(void* const* d_in, const int* in_sizes, int n_in,
                              void* d_out, int out_size, void* d_ws, size_t ws_size,
                              hipStream_t stream) {
  const float* feat1 = (const float*)d_in[0];
  const float* feat2 = (const float*)d_in[1];
  const float* w1    = (const float*)d_in[2];
  const float* b1    = (const float*)d_in[3];
  const float* w2    = (const float*)d_in[4];
  const float* b2    = (const float*)d_in[5];
  float* out = (float*)d_out;

  float* pooled = (float*)d_ws;                 // 4*81*256 floats
  float* a_arr  = pooled + 4 * 81 * 256;        // 4*81*256 floats

  corr_pool_kernel<<<1024, 256, 0, stream>>>(feat1, feat2, pooled);
  mlp_kernel<<<4 * 81, 256, 0, stream>>>(pooled, w1, b1, w2, b2, a_arr);
  out_kernel<<<4 * 9 * 16, 128, 0, stream>>>(feat1, feat2, a_arr, out);
}